// Round 4
// baseline (238.894 us; speedup 1.0000x reference)
//
#include <hip/hip_runtime.h>
#include <math.h>

#define EPS 1e-5f
#define T_LEN 8192
#define WAVES_PER_BLOCK 4

// One WAVE = one (b,c) row. No barriers, no LDS, no cross-wave coupling.
// Row = 32 chunks x 64 granules (float4); lane owns granule (c*64+lane).
// Depth-4 register-rotated load pipeline: consume buf[c&3], immediately
// re-issue load of chunk c+4 into the freed slot -> 4 loads always in
// flight, compiler emits counted vmcnt waits, issue never drains.
// Per chunk: wave64 Hillis-Steele scan of (sum,sumsq) via shfl_up (12
// permutes), exclusive prefix, readlane(63) chunk totals accumulated in
// a per-lane running offset (only serial link between chunks: 2 adds),
// 4-element causal replay in registers, coalesced float4 store.
__global__ __launch_bounds__(256, 8) void causal_ln_kernel(
    const float* __restrict__ x,
    const float* __restrict__ weight,
    const float* __restrict__ bias,
    float* __restrict__ out,
    int C)
{
    const int t    = threadIdx.x;        // 0..255
    const int lane = t & 63;
    const int wid  = t >> 6;             // wave 0..3
    const int row  = blockIdx.x * WAVES_PER_BLOCK + wid;

    const float wv = weight[row % C];
    const float bv = bias[row % C];

    const float4* xg = (const float4*)(x   + (long long)row * T_LEN);
    float4*       og = (float4*)(out + (long long)row * T_LEN);

    // prologue: chunks 0..3 in flight
    float4 buf[4];
#pragma unroll
    for (int j = 0; j < 4; ++j)
        buf[j] = xg[j * 64 + lane];

    float off1 = 0.f, off2 = 0.f;        // totals of all chunks < c

#pragma unroll
    for (int c = 0; c < 32; ++c) {
        float4 cur = buf[c & 3];
        if (c + 4 < 32)
            buf[c & 3] = xg[(c + 4) * 64 + lane];   // refill freed slot

        // lane-local granule sums
        float s  = cur.x + cur.y + cur.z + cur.w;
        float s2 = cur.x * cur.x + cur.y * cur.y
                 + cur.z * cur.z + cur.w * cur.w;

        // wave64 inclusive scan of (s, s2)
        float ws = s, ws2 = s2;
#pragma unroll
        for (int o = 1; o < 64; o <<= 1) {
            float a = __shfl_up(ws,  o, 64);
            float b = __shfl_up(ws2, o, 64);
            if (lane >= o) { ws += a; ws2 += b; }
        }

        // exclusive prefix within chunk
        float es  = __shfl_up(ws,  1, 64);
        float es2 = __shfl_up(ws2, 1, 64);
        if (lane == 0) { es = 0.f; es2 = 0.f; }

        float run  = off1 + es;
        float run2 = off2 + es2;
        float cnt  = (float)((c * 64 + lane) * 4);

        // causal replay of the 4 owned elements
        float xs[4] = {cur.x, cur.y, cur.z, cur.w};
#pragma unroll
        for (int i = 0; i < 4; ++i) {
            float xi = xs[i];
            run  += xi;
            run2 += xi * xi;
            cnt  += 1.f;
            float rcv  = __builtin_amdgcn_rcpf(cnt);
            float mean = run * rcv;
            float var  = fmaxf(run2 * rcv - mean * mean, 0.f);
            float rinv = __builtin_amdgcn_rsqf(var + EPS);
            xs[i] = (xi - mean) * rinv * wv + bv;
        }
        og[c * 64 + lane] = make_float4(xs[0], xs[1], xs[2], xs[3]);

        // carry chunk totals (uniform via readlane -> SGPR adds)
        off1 += __int_as_float(__builtin_amdgcn_readlane(__float_as_int(ws),  63));
        off2 += __int_as_float(__builtin_amdgcn_readlane(__float_as_int(ws2), 63));
    }
}

extern "C" void kernel_launch(void* const* d_in, const int* in_sizes, int n_in,
                              void* d_out, int out_size, void* d_ws, size_t ws_size,
                              hipStream_t stream) {
    const float* x      = (const float*)d_in[0];
    const float* weight = (const float*)d_in[1];
    const float* bias   = (const float*)d_in[2];
    float* out          = (float*)d_out;

    const int C = in_sizes[1];            // 512 (weight is [1,C,1])
    const int T = 8192;                   // time length per row
    const int rows = in_sizes[0] / T;     // B*C = 4096

    dim3 grid(rows / WAVES_PER_BLOCK), block(64 * WAVES_PER_BLOCK);
    hipLaunchKernelGGL(causal_ln_kernel, grid, block, 0, stream,
                       x, weight, bias, out, C);
}